// Round 3
// baseline (508.399 us; speedup 1.0000x reference)
//
#include <hip/hip_runtime.h>
#include <hip/hip_bf16.h>

#define NPTS 1024
#define EPSF 1e-7f

typedef const float* fp;
typedef __attribute__((ext_vector_type(8))) short short8;
typedef __attribute__((ext_vector_type(4))) float float4v;

// ---- ws layout (fp32 / dword elements) ----
// A0 [0,32768)      : feat@l0_fc0_w[0:40] + b0   (per point i)
// B0 [32768,65536)  : feat@l0_fc0_w[40:80]       (per point j)
// A1 [65536,98304)  : feat@l0_fc1_w[0:40] + b1
// B1 [98304,131072) : feat@l0_fc1_w[40:80]
#define OFF_B0   32768
#define OFF_A1   65536
#define OFF_B1   98304
#define OFF_FRAG 131072   // 16 frags * 256 dwords (64 lanes * 4 dwords = short8/lane)
// total 135168 dwords = 540,672 B

static __device__ __forceinline__ short f2bf(float x) {
    __hip_bfloat16 h = __float2bfloat16(x);
    short s; __builtin_memcpy(&s, &h, 2); return s;
}
static __device__ __forceinline__ unsigned pk2(float a, float b) {
    short sa = f2bf(a), sb = f2bf(b);
    unsigned short la, lb;
    __builtin_memcpy(&la, &sa, 2); __builtin_memcpy(&lb, &sb, 2);
    return (unsigned)la | ((unsigned)lb << 16);
}

union S8 { short8 s; unsigned u[4]; };

// blocks 0..1023   : per-point A/B partials
// blocks 1024..1039: fragment staging (bf16) for the weight mats:
//   frags 0..8  : A-frags of W^T (transposed layers) with output-feature permutation
//   frags 9..13 : B-frags of final_w (identity order, K=16 zero-padded to 32)
//   frags 14..15: stacked ppf-weight A-frags (k=0..3 -> W0p^T, k=4..7 -> W1p^T)
__global__ __launch_bounds__(128) void ppf_pre(
    fp feat, fp w0, fp b0, fp w1, fp b1,
    fp l0w2, fp l1w1, fp l1w2, fp l2w0, fp l2w1, fp l2w2, fp fw,
    float* __restrict__ ws)
{
    const int bid = blockIdx.x;
    const int t = threadIdx.x;
    if (bid < 1024) {
        __shared__ float f[40];
        int p = bid;
        if (t < 40) f[t] = feat[p * 40 + t];
        __syncthreads();
        int g = t >> 5;          // 0:A0 1:B0 2:A1 3:B1
        int c = t & 31;
        fp W = (g < 2) ? w0 : w1;
        int rowoff = (g & 1) ? 40 : 0;
        float acc = 0.f;
        if (!(g & 1)) acc = (g < 2) ? b0[c] : b1[c];
        #pragma unroll
        for (int k = 0; k < 40; ++k)
            acc += f[k] * W[(rowoff + k) * 32 + c];
        ws[g * 32768 + p * 32 + c] = acc;
    } else {
        // A-frag layout: lane l holds A[row=l&15][k=(l>>4)*8+j], j=0..7
        // B-frag layout: lane l holds B[k=(l>>4)*8+j][n=n0+(l&15)]
        int ff = bid - 1024;     // 0..15
        if (t >= 64) return;
        const int p  = t & 15;
        const int kq = t >> 4;
        const float* src = nullptr; int Kin = 0, Nsrc = 0, pm;
        switch (ff) {
            case 0:  src = l0w2; Kin = 32; Nsrc = 32; pm = 1; break; // l0w2^T half0
            case 1:  src = l0w2; Kin = 32; Nsrc = 32; pm = 2; break; // l0w2^T half1
            case 2:  src = l1w1; Kin = 32; Nsrc = 32; pm = 1; break;
            case 3:  src = l1w1; Kin = 32; Nsrc = 32; pm = 2; break;
            case 4:  src = l1w2; Kin = 32; Nsrc = 32; pm = 1; break;
            case 5:  src = l1w2; Kin = 32; Nsrc = 32; pm = 2; break;
            case 6:  src = l2w0; Kin = 32; Nsrc = 16; pm = 3; break; // 16-out perm
            case 7:  src = l2w1; Kin = 32; Nsrc = 16; pm = 3; break;
            case 8:  src = l2w2; Kin = 16; Nsrc = 16; pm = 3; break;
            case 14: pm = 4; break;                                  // stacked ppf W, pm1 rows
            case 15: pm = 5; break;                                  // stacked ppf W, pm2 rows
            default: src = fw;   Kin = 16; Nsrc = 66; pm = 0; break; // ff 9..13: final_w B-frags
        }
        // output-feature permutation (row p of the A-frag holds feature n):
        //  pm1: n = 8*(p>>2) + (p&3)        (lane q ends holding feats {8q..8q+3})
        //  pm2: n = 8*(p>>2) + 4 + (p&3)    (lane q ends holding feats {8q+4..8q+7})
        //  pm3: n = (q&1)*8 + (q>>1)*4 + (p&3)  -> lane^32 swap completes B/A layout
        int n;
        if      (pm == 0) n = (ff - 9) * 16 + p;
        else if (pm == 1) n = ((p >> 2) << 3) + (p & 3);
        else if (pm == 2) n = ((p >> 2) << 3) + 4 + (p & 3);
        else if (pm == 3) n = (((p >> 2) & 1) << 3) + (((p >> 3) & 1) << 2) + (p & 3);
        else              n = ((p >> 2) << 3) + ((pm == 5) ? 4 : 0) + (p & 3);
        unsigned dw[4];
        #pragma unroll
        for (int w = 0; w < 4; ++w) {
            unsigned short e[2];
            #pragma unroll
            for (int v = 0; v < 2; ++v) {
                int k = kq * 8 + w * 2 + v;
                float val;
                if (pm >= 4) {
                    // rows 80..83 of l0_fc0_w / l0_fc1_w, transposed, stacked on k
                    val = (k < 4) ? w0[(80 + k) * 32 + n]
                        : (k < 8) ? w1[(80 + k - 4) * 32 + n] : 0.f;
                } else {
                    val = (k < Kin && n < Nsrc) ? src[k * Nsrc + n] : 0.f;
                }
                short s = f2bf(val);
                __builtin_memcpy(&e[v], &s, 2);
            }
            dw[w] = (unsigned)e[0] | ((unsigned)e[1] << 16);
        }
        unsigned* dst = (unsigned*)ws + OFF_FRAG + ff * 256 + t * 4;
        #pragma unroll
        for (int w = 0; w < 4; ++w) dst[w] = dw[w];
    }
}

static __device__ __forceinline__ float4v mfma16(short8 a, short8 b, float4v c) {
    return __builtin_amdgcn_mfma_f32_16x16x32_bf16(a, b, c, 0, 0, 0);
}

// 4096 blocks x 256 threads, __launch_bounds__(256,4): target <=128 VGPR so
// 4 waves/SIMD co-reside (latency-bound kernel; TLP hides the serial
// MFMA->pack->MFMA chain). Only the hot-path frags (l0w2/l1w1/l1w2/ppf) stay
// persistent; L2 + final frags and cold biases reload per tile (L1-hot).
__global__ __launch_bounds__(256, 4) void ppf_main(
    fp pc, fp nrm, fp dist,
    fp l0b2, fp l1b1, fp l1b2, fp l2b0, fp l2b1, fp l2b2, fp fb,
    const float* __restrict__ ws, float* __restrict__ out)
{
    const int tid  = threadIdx.x;
    const int wv   = tid >> 6;
    const int lane = tid & 63;
    const int q    = lane >> 4;
    const int ml   = lane & 15;
    const int kb   = q * 8;

    const int i    = blockIdx.x >> 2;
    const int jblk = ((blockIdx.x & 3) << 8) + (wv << 6);

    // ---- persistent weight fragments (hot path only) ----
    const short8* fragp = (const short8*)(ws + OFF_FRAG);
    const short8 fa_l0w2_0 = fragp[0 * 64 + lane], fa_l0w2_1 = fragp[1 * 64 + lane];
    const short8 fa_l1w1_0 = fragp[2 * 64 + lane], fa_l1w1_1 = fragp[3 * 64 + lane];
    const short8 fa_l1w2_0 = fragp[4 * 64 + lane], fa_l1w2_1 = fragp[5 * 64 + lane];
    const short8 fa_ppf_0  = fragp[14 * 64 + lane];
    const short8 fa_ppf_1  = fragp[15 * 64 + lane];

    // ---- persistent small invariants ----
    const float4v* b2p = (const float4v*)(l0b2 + kb);
    const float4v b2lo = b2p[0], b2hi = b2p[1];
    const float4v bA1lo = *(const float4v*)(l1b1 + kb);      // rows 8q+rr
    const float4v bA1hi = *(const float4v*)(l1b1 + kb + 4);  // rows 8q+4+rr
    const int off16 = ((q & 1) << 3) + ((q >> 1) << 2);      // n16(q*4+rr) base
    float bfb[5];
    #pragma unroll
    for (int nt = 0; nt < 5; ++nt) { int c = nt * 16 + ml; bfb[nt] = (c < 66) ? fb[c] : 0.f; }

    const float pix = pc[i * 3], piy = pc[i * 3 + 1], piz = pc[i * 3 + 2];
    const float nix = nrm[i * 3], niy = nrm[i * 3 + 1], niz = nrm[i * 3 + 2];
    const float4v z4 = {0.f, 0.f, 0.f, 0.f};

    for (int tt = 0; tt < 4; ++tt) {
        const int j0 = jblk + tt * 16;
        const int jm = j0 + ml;

        // ---- per-tile reloads of i-invariant slices (L1-hot after tile 0) ----
        const float4v* a0p = (const float4v*)(ws + i * 32 + kb);
        const float4v a0lo = a0p[0], a0hi = a0p[1];
        const float4v* a1p = (const float4v*)(ws + OFF_A1 + i * 32 + kb);
        const float4v a1lo = a1p[0], a1hi = a1p[1];
        const float4v* b0p = (const float4v*)(ws + OFF_B0 + jm * 32 + kb);
        const float4v b0lo = b0p[0], b0hi = b0p[1];
        const float4v* b1p = (const float4v*)(ws + OFF_B1 + jm * 32 + kb);
        const float4v b1lo = b1p[0], b1hi = b1p[1];

        // ---- ppf (lane owns pair m=ml; redundant across quads) ----
        const float d   = dist[i * NPTS + jm];
        const float inv = 1.f / (d + EPSF);
        const float dx = (pix - pc[jm * 3]) * inv;
        const float dy = (piy - pc[jm * 3 + 1]) * inv;
        const float dz = (piz - pc[jm * 3 + 2]) * inv;
        const float njx = nrm[jm * 3], njy = nrm[jm * 3 + 1], njz = nrm[jm * 3 + 2];
        const float p0 = nix * dx + niy * dy + niz * dz;
        const float p1 = njx * dx + njy * dy + njz * dz;
        const float p2 = nix * njx + niy * njy + niz * njz;
        const float p3 = d;

        // ---- layer0 pre-acts via stacked ppf MFMA ----
        const unsigned pk01 = pk2(p0, p1), pk23 = pk2(p2, p3);
        S8 bp0, bp1;
        bp0.u[0] = pk01; bp0.u[1] = pk23; bp0.u[2] = 0;    bp0.u[3] = 0;
        bp1.u[0] = 0;    bp1.u[1] = 0;    bp1.u[2] = pk01; bp1.u[3] = pk23;
        float4v cu0lo, cu0hi, cu1lo, cu1hi;
        #pragma unroll
        for (int rr = 0; rr < 4; ++rr) {
            cu0lo[rr] = a0lo[rr] + b0lo[rr];
            cu0hi[rr] = a0hi[rr] + b0hi[rr];
            cu1lo[rr] = a1lo[rr] + b1lo[rr];
            cu1hi[rr] = a1hi[rr] + b1hi[rr];
        }
        const float4v u1lo = mfma16(fa_ppf_0, bp1.s, cu1lo);  // relu path, feats 8q+rr
        const float4v u1hi = mfma16(fa_ppf_1, bp1.s, cu1hi);  // feats 8q+4+rr
        const float4v u0lo = mfma16(fa_ppf_0, bp0.s, cu0lo);  // residual path
        const float4v u0hi = mfma16(fa_ppf_1, bp0.s, cu0hi);

        // ---- L0 (transposed): D = l0w2^T @ relu(u1)^T ----
        short8 ha;
        #pragma unroll
        for (int rr = 0; rr < 4; ++rr) {
            ha[rr]     = f2bf(fmaxf(u1lo[rr], 0.f));
            ha[4 + rr] = f2bf(fmaxf(u1hi[rr], 0.f));
        }
        float4v d0 = mfma16(fa_l0w2_0, ha, z4);   // rows = feats 8q+rr, col = pair ml
        float4v d1 = mfma16(fa_l0w2_1, ha, z4);   // rows = feats 8q+4+rr

        // x1 = D + u0 + b2 : slot-aligned register adds
        float x1a[8];
        #pragma unroll
        for (int rr = 0; rr < 4; ++rr) {
            x1a[rr]     = d0[rr] + u0lo[rr] + b2lo[rr];
            x1a[4 + rr] = d1[rr] + u0hi[rr] + b2hi[rr];
        }
        short8 x1b;
        #pragma unroll
        for (int jj = 0; jj < 8; ++jj) x1b[jj] = f2bf(x1a[jj]);

        // ---- L1 (transposed) ----
        float4v dh0 = mfma16(fa_l1w1_0, x1b, bA1lo);
        float4v dh1 = mfma16(fa_l1w1_1, x1b, bA1hi);
        short8 hb;
        #pragma unroll
        for (int rr = 0; rr < 4; ++rr) {
            hb[rr]     = f2bf(fmaxf(dh0[rr], 0.f));
            hb[4 + rr] = f2bf(fmaxf(dh1[rr], 0.f));
        }
        const float4v bA2lo = *(const float4v*)(l1b2 + kb);      // per-tile reload
        const float4v bA2hi = *(const float4v*)(l1b2 + kb + 4);
        float4v c20, c21;
        #pragma unroll
        for (int rr = 0; rr < 4; ++rr) {
            c20[rr] = x1a[rr]     + bA2lo[rr];
            c21[rr] = x1a[4 + rr] + bA2hi[rr];
        }
        float4v dx20 = mfma16(fa_l1w2_0, hb, c20);
        float4v dx21 = mfma16(fa_l1w2_1, hb, c21);
        short8 x2b;
        #pragma unroll
        for (int rr = 0; rr < 4; ++rr) {
            x2b[rr]     = f2bf(dx20[rr]);
            x2b[4 + rr] = f2bf(dx21[rr]);
        }

        // ---- L2 (transposed, 16-wide outputs); frags+biases per-tile (L1-hot) ----
        const short8 fa_l2w0 = fragp[6 * 64 + lane];
        const short8 fa_l2w1 = fragp[7 * 64 + lane];
        const short8 fa_l2w2 = fragp[8 * 64 + lane];
        const float4v b20v = *(const float4v*)(l2b0 + off16);
        const float4v b21v = *(const float4v*)(l2b1 + off16);
        const float4v b22v = *(const float4v*)(l2b2 + off16);
        float4v dr  = mfma16(fa_l2w0, x2b, b20v);   // residual path
        float4v dh2 = mfma16(fa_l2w1, x2b, b21v);
        // relu + pack + lane^32 swap -> B arrangement (k>=16 hits zero A cols)
        unsigned p01 = pk2(fmaxf(dh2[0], 0.f), fmaxf(dh2[1], 0.f));
        unsigned p23 = pk2(fmaxf(dh2[2], 0.f), fmaxf(dh2[3], 0.f));
        unsigned q01 = __shfl_xor(p01, 32);
        unsigned q23 = __shfl_xor(p23, 32);
        S8 h2u; h2u.u[0] = p01; h2u.u[1] = p23; h2u.u[2] = q01; h2u.u[3] = q23;
        float4v c3;
        #pragma unroll
        for (int rr = 0; rr < 4; ++rr) c3[rr] = dr[rr] + b22v[rr];
        float4v dx3 = mfma16(fa_l2w2, h2u.s, c3);   // x3: rows n16(q*4+rr), col ml

        // ---- final 16 -> 66 (original orientation), two halves to cap pressure ----
        unsigned r01 = pk2(dx3[0], dx3[1]);
        unsigned r23 = pk2(dx3[2], dx3[3]);
        unsigned s01 = __shfl_xor(r01, 32);
        unsigned s23 = __shfl_xor(r23, 32);
        S8 x3u; x3u.u[0] = r01; x3u.u[1] = r23; x3u.u[2] = s01; x3u.u[3] = s23;

        {   // half A: outputs 0..47
            const short8 fg_fw0 = fragp[9 * 64 + lane];
            const short8 fg_fw1 = fragp[10 * 64 + lane];
            const short8 fg_fw2 = fragp[11 * 64 + lane];
            float4v cf0 = {bfb[0], bfb[0], bfb[0], bfb[0]};
            float4v cf1 = {bfb[1], bfb[1], bfb[1], bfb[1]};
            float4v cf2 = {bfb[2], bfb[2], bfb[2], bfb[2]};
            float4v o0 = mfma16(x3u.s, fg_fw0, cf0);
            float4v o1 = mfma16(x3u.s, fg_fw1, cf1);
            float4v o2 = mfma16(x3u.s, fg_fw2, cf2);
            #pragma unroll
            for (int rr = 0; rr < 4; ++rr) {
                float* orow = out + (size_t)(i * NPTS + j0 + q * 4 + rr) * 66;
                orow[ml]      = o0[rr];
                orow[16 + ml] = o1[rr];
                orow[32 + ml] = o2[rr];
            }
        }
        {   // half B: outputs 48..65
            const short8 fg_fw3 = fragp[12 * 64 + lane];
            const short8 fg_fw4 = fragp[13 * 64 + lane];
            float4v cf3 = {bfb[3], bfb[3], bfb[3], bfb[3]};
            float4v cf4 = {bfb[4], bfb[4], bfb[4], bfb[4]};
            float4v o3 = mfma16(x3u.s, fg_fw3, cf3);
            float4v o4 = mfma16(x3u.s, fg_fw4, cf4);
            #pragma unroll
            for (int rr = 0; rr < 4; ++rr) {
                float* orow = out + (size_t)(i * NPTS + j0 + q * 4 + rr) * 66;
                orow[48 + ml] = o3[rr];
                if (ml < 2) orow[64 + ml] = o4[rr];
            }
        }
    }
}

extern "C" void kernel_launch(void* const* d_in, const int* in_sizes, int n_in,
                              void* d_out, int out_size, void* d_ws, size_t ws_size,
                              hipStream_t stream) {
    (void)in_sizes; (void)n_in; (void)out_size; (void)ws_size;
    fp pc   = (fp)d_in[0];
    fp nrm  = (fp)d_in[1];
    fp dist = (fp)d_in[2];
    fp feat = (fp)d_in[3];
    fp w0   = (fp)d_in[4];   fp b0   = (fp)d_in[5];
    fp w1   = (fp)d_in[6];   fp b1   = (fp)d_in[7];
    fp l0w2 = (fp)d_in[8];   fp l0b2 = (fp)d_in[9];
    fp l1w1 = (fp)d_in[10];  fp l1b1 = (fp)d_in[11];
    fp l1w2 = (fp)d_in[12];  fp l1b2 = (fp)d_in[13];
    fp l2w0 = (fp)d_in[14];  fp l2b0 = (fp)d_in[15];
    fp l2w1 = (fp)d_in[16];  fp l2b1 = (fp)d_in[17];
    fp l2w2 = (fp)d_in[18];  fp l2b2 = (fp)d_in[19];
    fp fw   = (fp)d_in[20];  fp fb   = (fp)d_in[21];
    float* ws  = (float*)d_ws;
    float* out = (float*)d_out;

    ppf_pre<<<1040, 128, 0, stream>>>(feat, w0, b0, w1, b1,
        l0w2, l1w1, l1w2, l2w0, l2w1, l2w2, fw, ws);

    ppf_main<<<4096, 256, 0, stream>>>(pc, nrm, dist,
        l0b2, l1b1, l1b2, l2b0, l2b1, l2b2, fb, ws, out);
}

// Round 4
// 377.987 us; speedup vs baseline: 1.3450x; 1.3450x over previous
//
#include <hip/hip_runtime.h>
#include <hip/hip_bf16.h>

#define NPTS 1024
#define EPSF 1e-7f

typedef const float* fp;
typedef __attribute__((ext_vector_type(8))) short short8;
typedef __attribute__((ext_vector_type(4))) float float4v;

// ---- ws layout (fp32 / dword elements) ----
// A0 [0,32768)      : feat@l0_fc0_w[0:40] + b0   (per point i)
// B0 [32768,65536)  : feat@l0_fc0_w[40:80]       (per point j)
// A1 [65536,98304)  : feat@l0_fc1_w[0:40] + b1
// B1 [98304,131072) : feat@l0_fc1_w[40:80]
#define OFF_B0   32768
#define OFF_A1   65536
#define OFF_B1   98304
#define OFF_FRAG 131072   // 16 frags * 256 dwords (64 lanes * 4 dwords = short8/lane)
// total 135168 dwords = 540,672 B

static __device__ __forceinline__ short f2bf(float x) {
    __hip_bfloat16 h = __float2bfloat16(x);
    short s; __builtin_memcpy(&s, &h, 2); return s;
}
static __device__ __forceinline__ unsigned pk2(float a, float b) {
    short sa = f2bf(a), sb = f2bf(b);
    unsigned short la, lb;
    __builtin_memcpy(&la, &sa, 2); __builtin_memcpy(&lb, &sb, 2);
    return (unsigned)la | ((unsigned)lb << 16);
}

union S8 { short8 s; unsigned u[4]; };

// blocks 0..1023   : per-point A/B partials
// blocks 1024..1039: fragment staging (bf16) for the weight mats:
//   frags 0..8  : A-frags of W^T (transposed layers) with output-feature permutation
//   frags 9..13 : B-frags of final_w (identity order, K=16 zero-padded to 32)
//   frags 14..15: stacked ppf-weight A-frags (k=0..3 -> W0p^T, k=4..7 -> W1p^T)
__global__ __launch_bounds__(128) void ppf_pre(
    fp feat, fp w0, fp b0, fp w1, fp b1,
    fp l0w2, fp l1w1, fp l1w2, fp l2w0, fp l2w1, fp l2w2, fp fw,
    float* __restrict__ ws)
{
    const int bid = blockIdx.x;
    const int t = threadIdx.x;
    if (bid < 1024) {
        __shared__ float f[40];
        int p = bid;
        if (t < 40) f[t] = feat[p * 40 + t];
        __syncthreads();
        int g = t >> 5;          // 0:A0 1:B0 2:A1 3:B1
        int c = t & 31;
        fp W = (g < 2) ? w0 : w1;
        int rowoff = (g & 1) ? 40 : 0;
        float acc = 0.f;
        if (!(g & 1)) acc = (g < 2) ? b0[c] : b1[c];
        #pragma unroll
        for (int k = 0; k < 40; ++k)
            acc += f[k] * W[(rowoff + k) * 32 + c];
        ws[g * 32768 + p * 32 + c] = acc;
    } else {
        // A-frag layout: lane l holds A[row=l&15][k=(l>>4)*8+j], j=0..7
        // B-frag layout: lane l holds B[k=(l>>4)*8+j][n=n0+(l&15)]
        int ff = bid - 1024;     // 0..15
        if (t >= 64) return;
        const int p  = t & 15;
        const int kq = t >> 4;
        const float* src = nullptr; int Kin = 0, Nsrc = 0, pm;
        switch (ff) {
            case 0:  src = l0w2; Kin = 32; Nsrc = 32; pm = 1; break; // l0w2^T half0
            case 1:  src = l0w2; Kin = 32; Nsrc = 32; pm = 2; break; // l0w2^T half1
            case 2:  src = l1w1; Kin = 32; Nsrc = 32; pm = 1; break;
            case 3:  src = l1w1; Kin = 32; Nsrc = 32; pm = 2; break;
            case 4:  src = l1w2; Kin = 32; Nsrc = 32; pm = 1; break;
            case 5:  src = l1w2; Kin = 32; Nsrc = 32; pm = 2; break;
            case 6:  src = l2w0; Kin = 32; Nsrc = 16; pm = 3; break; // 16-out perm
            case 7:  src = l2w1; Kin = 32; Nsrc = 16; pm = 3; break;
            case 8:  src = l2w2; Kin = 16; Nsrc = 16; pm = 3; break;
            case 14: pm = 4; break;                                  // stacked ppf W, pm1 rows
            case 15: pm = 5; break;                                  // stacked ppf W, pm2 rows
            default: src = fw;   Kin = 16; Nsrc = 66; pm = 0; break; // ff 9..13: final_w B-frags
        }
        // output-feature permutation (row p of the A-frag holds feature n):
        //  pm1: n = 8*(p>>2) + (p&3)        (lane q ends holding feats {8q..8q+3})
        //  pm2: n = 8*(p>>2) + 4 + (p&3)    (lane q ends holding feats {8q+4..8q+7})
        //  pm3: n = (q&1)*8 + (q>>1)*4 + (p&3)  -> lane^32 swap completes B/A layout
        int n;
        if      (pm == 0) n = (ff - 9) * 16 + p;
        else if (pm == 1) n = ((p >> 2) << 3) + (p & 3);
        else if (pm == 2) n = ((p >> 2) << 3) + 4 + (p & 3);
        else if (pm == 3) n = (((p >> 2) & 1) << 3) + (((p >> 3) & 1) << 2) + (p & 3);
        else              n = ((p >> 2) << 3) + ((pm == 5) ? 4 : 0) + (p & 3);
        unsigned dw[4];
        #pragma unroll
        for (int w = 0; w < 4; ++w) {
            unsigned short e[2];
            #pragma unroll
            for (int v = 0; v < 2; ++v) {
                int k = kq * 8 + w * 2 + v;
                float val;
                if (pm >= 4) {
                    // rows 80..83 of l0_fc0_w / l0_fc1_w, transposed, stacked on k
                    val = (k < 4) ? w0[(80 + k) * 32 + n]
                        : (k < 8) ? w1[(80 + k - 4) * 32 + n] : 0.f;
                } else {
                    val = (k < Kin && n < Nsrc) ? src[k * Nsrc + n] : 0.f;
                }
                short s = f2bf(val);
                __builtin_memcpy(&e[v], &s, 2);
            }
            dw[w] = (unsigned)e[0] | ((unsigned)e[1] << 16);
        }
        unsigned* dst = (unsigned*)ws + OFF_FRAG + ff * 256 + t * 4;
        #pragma unroll
        for (int w = 0; w < 4; ++w) dst[w] = dw[w];
    }
}

static __device__ __forceinline__ float4v mfma16(short8 a, short8 b, float4v c) {
    return __builtin_amdgcn_mfma_f32_16x16x32_bf16(a, b, c, 0, 0, 0);
}

// 4096 blocks x 256 threads. Block: i = bid>>2, j-range = (bid&3)*256.
// Wave wv handles j-subrange wv*64, 4 tiles of 16 pairs.
// All middle layers run operand-swapped (A = W^T frag, B = activations), with
// feature-permuted weight staging so layer outputs land directly in the next
// layer's B-operand register arrangement. The layer-0 pre-activations (ppf K=4
// GEMM + i/j partial sums) also run as MFMAs with exact fp32 partials in the
// C operand. No LDS, no lgkmcnt fences, no w0t/w1t register arrays.
// NOTE: no min-waves launch_bounds — (256,4) forced VGPR=64 and spilled the
// frag working set to scratch (+390 MB FETCH, main 12us -> 232us). Natural
// allocation (~160 VGPR, 3 waves/SIMD) is the verified optimum.
__global__ __launch_bounds__(256) void ppf_main(
    fp pc, fp nrm, fp dist,
    fp l0b2, fp l1b1, fp l1b2, fp l2b0, fp l2b1, fp l2b2, fp fb,
    const float* __restrict__ ws, float* __restrict__ out)
{
    const int tid  = threadIdx.x;
    const int wv   = tid >> 6;
    const int lane = tid & 63;
    const int q    = lane >> 4;
    const int ml   = lane & 15;
    const int kb   = q * 8;

    const int i    = blockIdx.x >> 2;
    const int jblk = ((blockIdx.x & 3) << 8) + (wv << 6);

    // ---- weight fragments, resident in VGPRs for the whole kernel ----
    const short8* fragp = (const short8*)(ws + OFF_FRAG);
    const short8 fa_l0w2_0 = fragp[0 * 64 + lane], fa_l0w2_1 = fragp[1 * 64 + lane];
    const short8 fa_l1w1_0 = fragp[2 * 64 + lane], fa_l1w1_1 = fragp[3 * 64 + lane];
    const short8 fa_l1w2_0 = fragp[4 * 64 + lane], fa_l1w2_1 = fragp[5 * 64 + lane];
    const short8 fa_l2w0   = fragp[6 * 64 + lane];
    const short8 fa_l2w1   = fragp[7 * 64 + lane];
    const short8 fa_l2w2   = fragp[8 * 64 + lane];
    const short8 fg_fw0 = fragp[9 * 64 + lane],  fg_fw1 = fragp[10 * 64 + lane];
    const short8 fg_fw2 = fragp[11 * 64 + lane], fg_fw3 = fragp[12 * 64 + lane];
    const short8 fg_fw4 = fragp[13 * 64 + lane];
    const short8 fa_ppf_0 = fragp[14 * 64 + lane];
    const short8 fa_ppf_1 = fragp[15 * 64 + lane];

    // ---- per-lane invariant slices ----
    const float4v* a0p = (const float4v*)(ws + i * 32 + kb);
    const float4v a0lo = a0p[0], a0hi = a0p[1];
    const float4v* a1p = (const float4v*)(ws + OFF_A1 + i * 32 + kb);
    const float4v a1lo = a1p[0], a1hi = a1p[1];
    const float4v* b2p = (const float4v*)(l0b2 + kb);
    const float4v b2lo = b2p[0], b2hi = b2p[1];
    // biases in D-layout rows (feature order = staged permutations)
    const float4v bA1lo = *(const float4v*)(l1b1 + kb);      // rows 8q+rr
    const float4v bA1hi = *(const float4v*)(l1b1 + kb + 4);  // rows 8q+4+rr
    const float4v bA2lo = *(const float4v*)(l1b2 + kb);
    const float4v bA2hi = *(const float4v*)(l1b2 + kb + 4);
    const int off16 = ((q & 1) << 3) + ((q >> 1) << 2);      // n16(q*4+rr) base
    const float4v b20v = *(const float4v*)(l2b0 + off16);
    const float4v b21v = *(const float4v*)(l2b1 + off16);
    const float4v b22v = *(const float4v*)(l2b2 + off16);
    float bfb[5];
    #pragma unroll
    for (int nt = 0; nt < 5; ++nt) { int c = nt * 16 + ml; bfb[nt] = (c < 66) ? fb[c] : 0.f; }

    const float pix = pc[i * 3], piy = pc[i * 3 + 1], piz = pc[i * 3 + 2];
    const float nix = nrm[i * 3], niy = nrm[i * 3 + 1], niz = nrm[i * 3 + 2];
    const float4v z4 = {0.f, 0.f, 0.f, 0.f};

    for (int tt = 0; tt < 4; ++tt) {
        const int j0 = jblk + tt * 16;
        const int jm = j0 + ml;

        // ---- ppf (lane owns pair m=ml; redundant across quads) ----
        const float d   = dist[i * NPTS + jm];
        const float inv = 1.f / (d + EPSF);
        const float dx = (pix - pc[jm * 3]) * inv;
        const float dy = (piy - pc[jm * 3 + 1]) * inv;
        const float dz = (piz - pc[jm * 3 + 2]) * inv;
        const float njx = nrm[jm * 3], njy = nrm[jm * 3 + 1], njz = nrm[jm * 3 + 2];
        const float p0 = nix * dx + niy * dy + niz * dz;
        const float p1 = njx * dx + njy * dy + njz * dz;
        const float p2 = nix * njx + niy * njy + niz * njz;
        const float p3 = d;

        const float4v* b0p = (const float4v*)(ws + OFF_B0 + jm * 32 + kb);
        const float4v b0lo = b0p[0], b0hi = b0p[1];
        const float4v* b1p = (const float4v*)(ws + OFF_B1 + jm * 32 + kb);
        const float4v b1lo = b1p[0], b1hi = b1p[1];

        // ---- layer0 pre-acts via stacked ppf MFMA ----
        // B operand: only k=0..7 rows (q=0 lanes) reach nonzero A columns.
        // bp0 -> k=0..3 = ppf (W0p half); bp1 -> k=4..7 = ppf (W1p half).
        const unsigned pk01 = pk2(p0, p1), pk23 = pk2(p2, p3);
        S8 bp0, bp1;
        bp0.u[0] = pk01; bp0.u[1] = pk23; bp0.u[2] = 0;    bp0.u[3] = 0;
        bp1.u[0] = 0;    bp1.u[1] = 0;    bp1.u[2] = pk01; bp1.u[3] = pk23;
        float4v cu0lo, cu0hi, cu1lo, cu1hi;
        #pragma unroll
        for (int rr = 0; rr < 4; ++rr) {
            cu0lo[rr] = a0lo[rr] + b0lo[rr];
            cu0hi[rr] = a0hi[rr] + b0hi[rr];
            cu1lo[rr] = a1lo[rr] + b1lo[rr];
            cu1hi[rr] = a1hi[rr] + b1hi[rr];
        }
        const float4v u1lo = mfma16(fa_ppf_0, bp1.s, cu1lo);  // relu path, feats 8q+rr
        const float4v u1hi = mfma16(fa_ppf_1, bp1.s, cu1hi);  // feats 8q+4+rr
        const float4v u0lo = mfma16(fa_ppf_0, bp0.s, cu0lo);  // residual path
        const float4v u0hi = mfma16(fa_ppf_1, bp0.s, cu0hi);

        // ---- L0 (transposed): D = l0w2^T @ relu(u1)^T ----
        short8 ha;
        #pragma unroll
        for (int rr = 0; rr < 4; ++rr) {
            ha[rr]     = f2bf(fmaxf(u1lo[rr], 0.f));
            ha[4 + rr] = f2bf(fmaxf(u1hi[rr], 0.f));
        }
        float4v d0 = mfma16(fa_l0w2_0, ha, z4);   // rows = feats 8q+rr, col = pair ml
        float4v d1 = mfma16(fa_l0w2_1, ha, z4);   // rows = feats 8q+4+rr

        // x1 = D + u0 + b2 : slot-aligned register adds (no transpose needed)
        float x1a[8];
        #pragma unroll
        for (int rr = 0; rr < 4; ++rr) {
            x1a[rr]     = d0[rr] + u0lo[rr] + b2lo[rr];
            x1a[4 + rr] = d1[rr] + u0hi[rr] + b2hi[rr];
        }
        short8 x1b;
        #pragma unroll
        for (int jj = 0; jj < 8; ++jj) x1b[jj] = f2bf(x1a[jj]);

        // ---- L1 (transposed) ----
        float4v dh0 = mfma16(fa_l1w1_0, x1b, bA1lo);
        float4v dh1 = mfma16(fa_l1w1_1, x1b, bA1hi);
        short8 hb;
        #pragma unroll
        for (int rr = 0; rr < 4; ++rr) {
            hb[rr]     = f2bf(fmaxf(dh0[rr], 0.f));
            hb[4 + rr] = f2bf(fmaxf(dh1[rr], 0.f));
        }
        float4v c20, c21;
        #pragma unroll
        for (int rr = 0; rr < 4; ++rr) {
            c20[rr] = x1a[rr]     + bA2lo[rr];
            c21[rr] = x1a[4 + rr] + bA2hi[rr];
        }
        float4v dx20 = mfma16(fa_l1w2_0, hb, c20);
        float4v dx21 = mfma16(fa_l1w2_1, hb, c21);
        short8 x2b;
        #pragma unroll
        for (int rr = 0; rr < 4; ++rr) {
            x2b[rr]     = f2bf(dx20[rr]);
            x2b[4 + rr] = f2bf(dx21[rr]);
        }

        // ---- L2 (transposed, 16-wide outputs) ----
        float4v dr  = mfma16(fa_l2w0, x2b, b20v);   // residual path
        float4v dh2 = mfma16(fa_l2w1, x2b, b21v);
        // relu + pack + lane^32 swap -> B arrangement (k<16 real; k>=16 hits
        // zero-padded A columns, duplicate values are harmless & finite)
        unsigned p01 = pk2(fmaxf(dh2[0], 0.f), fmaxf(dh2[1], 0.f));
        unsigned p23 = pk2(fmaxf(dh2[2], 0.f), fmaxf(dh2[3], 0.f));
        unsigned q01 = __shfl_xor(p01, 32);
        unsigned q23 = __shfl_xor(p23, 32);
        S8 h2u; h2u.u[0] = p01; h2u.u[1] = p23; h2u.u[2] = q01; h2u.u[3] = q23;
        float4v c3;
        #pragma unroll
        for (int rr = 0; rr < 4; ++rr) c3[rr] = dr[rr] + b22v[rr];
        float4v dx3 = mfma16(fa_l2w2, h2u.s, c3);   // x3: rows n16(q*4+rr), col ml

        // ---- final 16 -> 66 (original orientation: A = x3, B = fw frags) ----
        // x3 -> A-layout via the same lane^32 swap (k>=16 hits zero B rows)
        unsigned r01 = pk2(dx3[0], dx3[1]);
        unsigned r23 = pk2(dx3[2], dx3[3]);
        unsigned s01 = __shfl_xor(r01, 32);
        unsigned s23 = __shfl_xor(r23, 32);
        S8 x3u; x3u.u[0] = r01; x3u.u[1] = r23; x3u.u[2] = s01; x3u.u[3] = s23;

        float4v cf0 = {bfb[0], bfb[0], bfb[0], bfb[0]};
        float4v cf1 = {bfb[1], bfb[1], bfb[1], bfb[1]};
        float4v cf2 = {bfb[2], bfb[2], bfb[2], bfb[2]};
        float4v cf3 = {bfb[3], bfb[3], bfb[3], bfb[3]};
        float4v cf4 = {bfb[4], bfb[4], bfb[4], bfb[4]};
        float4v o0 = mfma16(x3u.s, fg_fw0, cf0);
        float4v o1 = mfma16(x3u.s, fg_fw1, cf1);
        float4v o2 = mfma16(x3u.s, fg_fw2, cf2);
        float4v o3 = mfma16(x3u.s, fg_fw3, cf3);
        float4v o4 = mfma16(x3u.s, fg_fw4, cf4);

        // ---- store: lane covers rows q*4+rr, cols {ml, 16+ml, 32+ml, 48+ml, 64+ml(<66)} ----
        #pragma unroll
        for (int rr = 0; rr < 4; ++rr) {
            float* orow = out + (size_t)(i * NPTS + j0 + q * 4 + rr) * 66;
            orow[ml]      = o0[rr];
            orow[16 + ml] = o1[rr];
            orow[32 + ml] = o2[rr];
            orow[48 + ml] = o3[rr];
            if (ml < 2) orow[64 + ml] = o4[rr];
        }
    }
}

extern "C" void kernel_launch(void* const* d_in, const int* in_sizes, int n_in,
                              void* d_out, int out_size, void* d_ws, size_t ws_size,
                              hipStream_t stream) {
    (void)in_sizes; (void)n_in; (void)out_size; (void)ws_size;
    fp pc   = (fp)d_in[0];
    fp nrm  = (fp)d_in[1];
    fp dist = (fp)d_in[2];
    fp feat = (fp)d_in[3];
    fp w0   = (fp)d_in[4];   fp b0   = (fp)d_in[5];
    fp w1   = (fp)d_in[6];   fp b1   = (fp)d_in[7];
    fp l0w2 = (fp)d_in[8];   fp l0b2 = (fp)d_in[9];
    fp l1w1 = (fp)d_in[10];  fp l1b1 = (fp)d_in[11];
    fp l1w2 = (fp)d_in[12];  fp l1b2 = (fp)d_in[13];
    fp l2w0 = (fp)d_in[14];  fp l2b0 = (fp)d_in[15];
    fp l2w1 = (fp)d_in[16];  fp l2b1 = (fp)d_in[17];
    fp l2w2 = (fp)d_in[18];  fp l2b2 = (fp)d_in[19];
    fp fw   = (fp)d_in[20];  fp fb   = (fp)d_in[21];
    float* ws  = (float*)d_ws;
    float* out = (float*)d_out;

    ppf_pre<<<1040, 128, 0, stream>>>(feat, w0, b0, w1, b1,
        l0w2, l1w1, l1w2, l2w0, l2w1, l2w2, fw, ws);

    ppf_main<<<4096, 256, 0, stream>>>(pc, nrm, dist,
        l0b2, l1b1, l1b2, l2b0, l2b1, l2b2, fb, ws, out);
}